// Round 5
// baseline (6169.049 us; speedup 1.0000x reference)
//
#include <hip/hip_runtime.h>

#define B_   64
#define T_   512
#define D_   512
#define H_   1024
#define G4   4096      // 4*H
#define KTOT 1536      // D + H
#define KC_N 48        // KTOT / 32
#define AP   1544      // padded LDS A-row stride (1536 + 8 shorts)

typedef float f32x4 __attribute__((ext_vector_type(4)));
typedef short s16x8 __attribute__((ext_vector_type(8)));

__device__ __forceinline__ unsigned short f2bf(float f) {
    unsigned int u = __float_as_uint(f);
    u = (u + 0x7fffu + ((u >> 16) & 1u)) >> 16;   // RNE
    return (unsigned short)u;
}
__device__ __forceinline__ float bf2f(unsigned short h) {
    return __uint_as_float(((unsigned int)h) << 16);
}
__device__ __forceinline__ float sigm(float x) { return 1.f / (1.f + __expf(-x)); }
__device__ __forceinline__ float tanh_f(float x) { return 1.f - 2.f / (__expf(2.f * x) + 1.f); }

// Pack [W_ih | W_hh] into exact MFMA B-fragment order, bf16, gate-interleaved
// packed col n = 4*j_hidden + gate. Wpk[(((c*48 + kc)*64 + lane))*8 + j] =
// W[row(n)][k], n = c*16 + (lane&15), k = kc*32 + (lane>>4)*8 + j.
__global__ __launch_bounds__(256) void pack_w(const float* __restrict__ W_ih,
                                              const float* __restrict__ W_hh,
                                              unsigned short* __restrict__ Wpk) {
    int tid = blockIdx.x * 256 + threadIdx.x;        // [0, 256*48*64*8)
    int j    = tid & 7;
    int lane = (tid >> 3) & 63;
    int rest = tid >> 9;
    int kc = rest % KC_N;
    int c  = rest / KC_N;
    int npk = c * 16 + (lane & 15);
    int jh = npk >> 2, g = npk & 3;
    int row = g * H_ + jh;                           // torch gate order i,f,g,o
    int k = kc * 32 + (lane >> 4) * 8 + j;
    float v = (k < D_) ? W_ih[row * D_ + k] : W_hh[row * H_ + (k - D_)];
    Wpk[tid] = f2bf(v);
}

__global__ __launch_bounds__(256) void init_state(const float* __restrict__ h0,
                                                  const float* __restrict__ b_ih,
                                                  const float* __restrict__ b_hh,
                                                  float* __restrict__ bias_p,
                                                  unsigned long long* __restrict__ mb0) {
    int tid = blockIdx.x * 256 + threadIdx.x;        // 65536
    if (tid < G4) {                                  // bias in packed-col order
        int jh = tid >> 2, g = tid & 3;
        bias_p[tid] = b_ih[g * H_ + jh] + b_hh[g * H_ + jh];
    }
    if (tid < B_ * (H_ / 2)) {                       // mb0: h0 pairs, tag 0
        int c = tid & 511;
        unsigned int hv = (unsigned int)f2bf(h0[2 * c]) |
                          ((unsigned int)f2bf(h0[2 * c + 1]) << 16);
        mb0[tid] = (unsigned long long)hv;           // hi32 tag = 0
    }
}

// Persistent recurrence: 256 blocks = 4 batch groups x 64 col blocks, all 512
// steps in one plain launch (grid == #CUs -> co-resident at 1 block/CU).
// Weights in registers. Cross-block h exchange via TAG-IN-DATA mailbox:
// one relaxed agent-scope u64 slot = {step tag | 2 x bf16 h}. Validity and
// payload arrive in one atomic word -> single MALL round trip per step, no
// fences, no flags, no post-publish barrier. Two mailboxes alternate; the
// all-to-all dependency bounds skew so a buffer is never overwritten while
// readable (P writes tag t+3 only after consuming all t+2 publishes, which
// each block emits only after finishing its t+1 gather).
__global__ __launch_bounds__(256, 1) void lstm_persist(
    const float* __restrict__ x, const int* __restrict__ mask,
    const unsigned short* __restrict__ Wpk, const float* __restrict__ bias_p,
    const float* __restrict__ h0, const float* __restrict__ c0,
    unsigned long long* __restrict__ mb0, unsigned long long* __restrict__ mb1,
    float* __restrict__ out)
{
    __shared__ __align__(16) unsigned short At[16 * AP];  // [x_t | h] tile, bf16
    __shared__ float Dl[16][66];                          // gates f32, padded

    const int tid = threadIdx.x;
    const int blk = blockIdx.x;
    const int bg  = blk & 3;                 // batch group 0..3
    const int bxc = blk >> 2;                // col block 0..63
    const int b0  = bg * 16;
    const int w = tid >> 6, l = tid & 63;
    const int quad = l >> 4, l15 = l & 15;
    const int cgrp = bxc * 4 + w;            // global 16-col group [0,256)

    // ---- load this wave's weight slice into registers (once) ----
    s16x8 wf[KC_N];                          // 192 regs (unified VGPR/AGPR file)
    const unsigned short* wbase = Wpk + ((size_t)cgrp * KC_N * 64 + l) * 8;
    #pragma unroll
    for (int kc = 0; kc < KC_N; ++kc)
        wf[kc] = *reinterpret_cast<const s16x8*>(wbase + (size_t)kc * 64 * 8);

    // epilogue thread identity: (batch eb, hidden eu); thread OWNS (row,col)
    const int eb = tid >> 4, eu = tid & 15;
    const int jh = bxc * 16 + eu;
    const float4 bias = *reinterpret_cast<const float4*>(bias_p + bxc * 64 + eu * 4);
    float c_val  = c0[jh];                   // thread-private fp32 carries
    float h_prev = h0[jh];

    for (int t = 0; t < T_; ++t) {
        unsigned long long* mbr = ((t & 1) ? mb1 : mb0) + (size_t)b0 * (H_ / 2);
        unsigned long long* mbw = (((t + 1) & 1) ? mb1 : mb0);
        const unsigned int want = (unsigned int)t;

        // ---- first-pass mailbox poll: issue all 32 loads (latency hides
        //      under x staging below) ----
        unsigned long long pv[32];
        #pragma unroll
        for (int i = 0; i < 32; ++i)
            pv[i] = __hip_atomic_load(&mbr[i * 256 + tid], __ATOMIC_RELAXED,
                                      __HIP_MEMORY_SCOPE_AGENT);

        // ---- prefetch mask ----
        const int m = mask[(b0 + eb) * T_ + t];

        // ---- stage x_t (fp32 -> bf16); no cross-block dependency ----
        #pragma unroll
        for (int i = 0; i < 8; ++i) {
            int e = i * 256 + tid;           // 16 rows x 128 float4
            int r = e >> 7, c4 = e & 127;
            float4 v = *reinterpret_cast<const float4*>(
                x + ((size_t)(b0 + r) * T_ + t) * D_ + c4 * 4);
            unsigned int lo = ((unsigned int)f2bf(v.y) << 16) | f2bf(v.x);
            unsigned int hi = ((unsigned int)f2bf(v.w) << 16) | f2bf(v.z);
            *reinterpret_cast<uint2*>(&At[r * AP + c4 * 4]) = make_uint2(lo, hi);
        }

        // ---- resolve mailbox: tag-checked writes to At-h; re-poll stragglers.
        //      (At-h is safe to write: all step t-1 MFMA reads ended before the
        //       previous Dl barrier.) ----
        unsigned int pend = 0;
        #pragma unroll
        for (int i = 0; i < 32; ++i) {
            unsigned long long v = pv[i];
            int e = i * 256 + tid, r = e >> 9, c = e & 511;
            if ((unsigned int)(v >> 32) == want)
                *reinterpret_cast<unsigned int*>(&At[r * AP + D_ + c * 2]) =
                    (unsigned int)v;
            else
                pend |= (1u << i);
        }
        while (pend) {
            unsigned int p = pend, np = 0;
            while (p) {
                int i = __ffs(p) - 1; p &= p - 1;
                int e = i * 256 + tid, r = e >> 9, c = e & 511;
                unsigned long long v = __hip_atomic_load(
                    &mbr[e], __ATOMIC_RELAXED, __HIP_MEMORY_SCOPE_AGENT);
                if ((unsigned int)(v >> 32) == want)
                    *reinterpret_cast<unsigned int*>(&At[r * AP + D_ + c * 2]) =
                        (unsigned int)v;
                else
                    np |= (1u << i);
            }
            pend = np;
            if (pend) __builtin_amdgcn_s_sleep(1);
        }
        __syncthreads();                     // SYNC1: At (x|h) ready

        // ---- MFMA: 48 k-chunks, 4 independent acc chains ----
        f32x4 acc0 = {0.f,0.f,0.f,0.f}, acc1 = {0.f,0.f,0.f,0.f};
        f32x4 acc2 = {0.f,0.f,0.f,0.f}, acc3 = {0.f,0.f,0.f,0.f};
        const unsigned short* atp = &At[l15 * AP + quad * 8];
        #pragma unroll
        for (int kc = 0; kc < KC_N; kc += 4) {
            s16x8 a0 = *reinterpret_cast<const s16x8*>(atp + (kc + 0) * 32);
            s16x8 a1 = *reinterpret_cast<const s16x8*>(atp + (kc + 1) * 32);
            s16x8 a2 = *reinterpret_cast<const s16x8*>(atp + (kc + 2) * 32);
            s16x8 a3 = *reinterpret_cast<const s16x8*>(atp + (kc + 3) * 32);
            acc0 = __builtin_amdgcn_mfma_f32_16x16x32_bf16(a0, wf[kc + 0], acc0, 0, 0, 0);
            acc1 = __builtin_amdgcn_mfma_f32_16x16x32_bf16(a1, wf[kc + 1], acc1, 0, 0, 0);
            acc2 = __builtin_amdgcn_mfma_f32_16x16x32_bf16(a2, wf[kc + 2], acc2, 0, 0, 0);
            acc3 = __builtin_amdgcn_mfma_f32_16x16x32_bf16(a3, wf[kc + 3], acc3, 0, 0, 0);
        }
        f32x4 accs = (acc0 + acc1) + (acc2 + acc3);
        #pragma unroll
        for (int r = 0; r < 4; ++r)          // C/D: col=lane&15, row=quad*4+r
            Dl[quad * 4 + r][w * 16 + l15] = accs[r];
        __syncthreads();                     // SYNC2: Dl ready

        // ---- fused LSTM cell epilogue (h_old, c are register carries) ----
        float gi = sigm  (Dl[eb][eu * 4 + 0] + bias.x);
        float gf = sigm  (Dl[eb][eu * 4 + 1] + bias.y);
        float gg = tanh_f(Dl[eb][eu * 4 + 2] + bias.z);
        float go = sigm  (Dl[eb][eu * 4 + 3] + bias.w);
        float c_new = gf * c_val + gi * gg;
        float h_new = go * tanh_f(c_new);
        float h2 = m ? h_new : h_prev;
        c_val    = m ? c_new : c_val;
        h_prev   = h2;
        out[((size_t)(b0 + eb) * T_ + t) * H_ + jh] = h2;

        // ---- publish: pair bf16 via shfl, even threads store ONE u64
        //      {tag t+1 | h pair}. No fence, no flag, no barrier. ----
        unsigned short hu = f2bf(h2);
        unsigned int partner =
            (unsigned int)(unsigned short)__shfl_xor((int)hu, 1);
        unsigned int hv = (unsigned int)hu | (partner << 16);
        if (!(tid & 1)) {
            unsigned long long pk =
                ((unsigned long long)(unsigned int)(t + 1) << 32) | hv;
            __hip_atomic_store(&mbw[(size_t)(b0 + eb) * (H_ / 2) + (jh >> 1)],
                               pk, __ATOMIC_RELAXED, __HIP_MEMORY_SCOPE_AGENT);
        }
    }
}

extern "C" void kernel_launch(void* const* d_in, const int* in_sizes, int n_in,
                              void* d_out, int out_size, void* d_ws, size_t ws_size,
                              hipStream_t stream)
{
    const float* x    = (const float*)d_in[0];
    const int*   mask = (const int*)d_in[1];
    const float* W_ih = (const float*)d_in[2];
    const float* W_hh = (const float*)d_in[3];
    const float* b_ih = (const float*)d_in[4];
    const float* b_hh = (const float*)d_in[5];
    const float* h0   = (const float*)d_in[6];
    const float* c0   = (const float*)d_in[7];
    float* out = (float*)d_out;

    // ws layout (~13.1 MB)
    char* wsb = (char*)d_ws;
    unsigned short*     Wpk    = (unsigned short*)(wsb);            // 12,582,912 B
    float*              bias_p = (float*)(wsb + 12582912);          //     16,384 B
    unsigned long long* mb0    = (unsigned long long*)(wsb + 12599296); // 262,144 B
    unsigned long long* mb1    = (unsigned long long*)(wsb + 12861440); // 262,144 B

    // ws re-poisoned every call -> re-pack + re-init every call (~15 us)
    pack_w<<<24576, 256, 0, stream>>>(W_ih, W_hh, Wpk);
    init_state<<<256, 256, 0, stream>>>(h0, b_ih, b_hh, bias_p, mb0);

    lstm_persist<<<dim3(256), dim3(256), 0, stream>>>(
        x, mask, Wpk, bias_p, h0, c0, mb0, mb1, out);
}